// Round 2
// baseline (1010.539 us; speedup 1.0000x reference)
//
#include <hip/hip_runtime.h>
#include <stdint.h>
#include <stddef.h>

// GraphConvolution: out = relu( sum_s adj[s] @ (x @ W[s] + b[s]) )
// N=8192, S=3, D_IN=D_OUT=32.  adj (805 MB fp32) dominates -> HBM-bound,
// floor ~128 us at 6.3 TB/s.
//
// R1 post-mortem: phase rotation + depth-2 prefetch = neutral (1013->995).
// Lockstep-channel theory dead.  Surviving theory: (a) 1 KB-per-row-visit
// segments at 32 KB stride are DRAM-activate-bound (~25% eff; the poison
// fill hits 6.4 TB/s sequential on the same chip); (b) B (preT) tiles are
// re-read per block (786 MB total) and rotation pushed them out of L2.
// R2 design: M-tile 32 x KB 1024 (4 KB contiguous per row-visit, 4x
// bytes/activate), 256 blocks x 1024 thr in natural lockstep so all blocks
// share one L2-hot 64 KB B-tile; B issued before A-prefetch each iter so
// the in-order vmcnt wait on B does not drain the A pipeline.

static constexpr int NN = 8192;
static constexpr int DD = 32;
static constexpr int SS = 3;
static constexpr int KB = 1024;            // k per chunk -> 4 KB/row segments
static constexpr int MT = 32;              // M rows per block
static constexpr int NCH = SS * NN / KB;   // 24 chunks

typedef __attribute__((ext_vector_type(8))) short short8;   // 8 bf16 = 16 B
typedef __attribute__((ext_vector_type(4))) float floatx4;  // 16 B

__device__ __forceinline__ unsigned short f2bf(float f) {
  // round-to-nearest-even fp32 -> bf16
  unsigned int u = __float_as_uint(f);
  u += 0x7FFFu + ((u >> 16) & 1u);
  return (unsigned short)(u >> 16);
}

__device__ __forceinline__ void barrier_no_vm_drain() {
  // __syncthreads() lowers with s_waitcnt vmcnt(0) before s_barrier,
  // draining the global prefetch queue. We only need LDS ordering.
  asm volatile("s_waitcnt lgkmcnt(0)\n\ts_barrier" ::: "memory");
}

// Kernel 1: preT[s][n][k] = (x @ W[s] + b[s])[k][n]  stored transposed, bf16.
extern "C" __global__ void __launch_bounds__(256)
pre_kernel(const float* __restrict__ x, const float* __restrict__ W,
           const float* __restrict__ b, unsigned short* __restrict__ preT) {
  __shared__ float xs[256 * 33];
  __shared__ float Ws[DD * DD];
  __shared__ float bs[DD];
  const int t = threadIdx.x;
  const int s = blockIdx.y;
  const int kbase = blockIdx.x * 256;

  #pragma unroll
  for (int j = 0; j < 32; ++j) {
    int idx = j * 256 + t;
    xs[(idx >> 5) * 33 + (idx & 31)] = x[kbase * DD + idx];
  }
  #pragma unroll
  for (int j = 0; j < 4; ++j) Ws[j * 256 + t] = W[s * DD * DD + j * 256 + t];
  if (t < DD) bs[t] = b[s * DD + t];
  __syncthreads();

  float xr[32];
  #pragma unroll
  for (int i = 0; i < 32; ++i) xr[i] = xs[t * 33 + i];

  unsigned short* o = preT + (size_t)s * DD * NN + kbase + t;
  #pragma unroll
  for (int n = 0; n < DD; ++n) {
    float acc = bs[n];
    #pragma unroll
    for (int i = 0; i < 32; ++i) acc += xr[i] * Ws[i * DD + n];
    o[(size_t)n * NN] = f2bf(acc);
  }
}

// Kernel 2: out[m][n] = relu( sum_s sum_k adj[s][m][k] * pre[s][k][n] )
// 256 blocks x 1024 threads (16 waves).  Per chunk: stage 32 rows x 4 KB of
// adj (fp32 -> bf16) into a 64 KB LDS buffer (double-buffered = 128 KB);
// wave w = (msub = w>>3, kgroup = w&7) runs 4 MFMA k-steps on rows
// msub*16..+15.  Pipeline: B(cur) loads -> A(next) loads -> LDS write of
// pre-converted W regs -> lgkm-only barrier -> MFMA -> convert A(next)->W.
extern "C" __global__ void __launch_bounds__(1024, 4)
prop_kernel(const float* __restrict__ adj, const unsigned short* __restrict__ preT,
            float* __restrict__ out) {
  const int tid  = threadIdx.x;
  const int wave = tid >> 6;
  const int lane = tid & 63;
  const int q = lane >> 4;        // 0..3
  const int c = lane & 15;        // 0..15
  const int msub   = wave >> 3;   // 0..1 : which 16-row half of the M-tile
  const int kgroup = wave & 7;    // 0..7 : which 32-wide k-step group
  const int m0 = blockIdx.x * MT;

  __shared__ unsigned short As[2][MT * KB];   // 128 KB (m201 precedent)

  // Staging map: thread t owns row (t>>5), 128 B contiguous at col (t&31)*8,
  // as 4 j-slices of 8 floats at stride 256 (so LDS writes are lane-contiguous).
  const int srow = tid >> 5;      // 0..31
  const int lr   = tid & 31;      // 0..31
  const float* gA = adj + (size_t)(m0 + srow) * NN + lr * 8;

  // B fragment base: preT[c][kgroup*32 + q*8 ...] (L2-resident, lockstep-shared)
  const unsigned short* gB = preT + (size_t)c * NN + kgroup * 32 + q * 8;

  auto a_addr = [&](int id) -> const float* {
    return gA + ((size_t)(id >> 3) << 26) + ((size_t)(id & 7) << 10);
  };
  auto b_addr = [&](int id) -> const unsigned short* {
    return gB + ((size_t)(id >> 3) << 18) + ((size_t)(id & 7) << 10);
  };

  floatx4 acc0 = {0.f, 0.f, 0.f, 0.f};
  floatx4 acc1 = {0.f, 0.f, 0.f, 0.f};

  // Prologue: load + convert chunk 0 into W regs (one-time stall).
  short8 W[4];
  {
    const float* p = a_addr(0);
    #pragma unroll
    for (int j = 0; j < 4; ++j) {
      floatx4 a0 = *(const floatx4*)(p + j * 256);
      floatx4 a1 = *(const floatx4*)(p + j * 256 + 4);
      short8 w;
      w[0] = (short)f2bf(a0[0]); w[1] = (short)f2bf(a0[1]);
      w[2] = (short)f2bf(a0[2]); w[3] = (short)f2bf(a0[3]);
      w[4] = (short)f2bf(a1[0]); w[5] = (short)f2bf(a1[1]);
      w[6] = (short)f2bf(a1[2]); w[7] = (short)f2bf(a1[3]);
      W[j] = w;
    }
  }

  unsigned short* const dst0 = &As[0][srow * KB + lr * 8];
  unsigned short* const dst1 = &As[1][srow * KB + lr * 8];
  const unsigned short* const af0 = &As[0][(msub * 16 + c) * KB + kgroup * 32 + q * 8];
  const unsigned short* const af1 = &As[1][(msub * 16 + c) * KB + kgroup * 32 + q * 8];

  for (int ch = 0; ch < NCH; ++ch) {
    // (1) B for current chunk — issued FIRST so the pre-MFMA vmcnt wait
    //     (in-order counter!) does not force the A prefetch to drain.
    const unsigned short* pb = b_addr(ch);
    short8 B0[4], B1[4];
    #pragma unroll
    for (int j = 0; j < 4; ++j) {
      B0[j] = *(const short8*)(pb + j * 256);
      B1[j] = *(const short8*)(pb + j * 256 + 16 * NN);
    }

    // (2) A prefetch for next chunk (tail: harmless reload of chunk 23).
    const int chn = (ch + 1 < NCH) ? ch + 1 : ch;
    const float* pa = a_addr(chn);
    floatx4 NA[8];
    #pragma unroll
    for (int j = 0; j < 4; ++j) {
      NA[2 * j]     = *(const floatx4*)(pa + j * 256);
      NA[2 * j + 1] = *(const floatx4*)(pa + j * 256 + 4);
    }

    // (3) Commit current chunk (pre-converted W regs) to LDS — no vm wait.
    unsigned short* dst = (ch & 1) ? dst1 : dst0;
    #pragma unroll
    for (int j = 0; j < 4; ++j)
      *(short8*)(dst + j * 256) = W[j];

    barrier_no_vm_drain();  // lgkm only: A/B loads stay in flight

    // (4) MFMA: this wave's 4 k-steps (k = jj*256 + kgroup*32).
    const unsigned short* af = (ch & 1) ? af1 : af0;
    #pragma unroll
    for (int jj = 0; jj < 4; ++jj) {
      const short8 a = *(const short8*)(af + jj * 256);
      acc0 = __builtin_amdgcn_mfma_f32_16x16x32_bf16(a, B0[jj], acc0, 0, 0, 0);
      acc1 = __builtin_amdgcn_mfma_f32_16x16x32_bf16(a, B1[jj], acc1, 0, 0, 0);
    }

    // (5) Convert next chunk's A to bf16 regs (load latency covered by 3+4).
    #pragma unroll
    for (int j = 0; j < 4; ++j) {
      floatx4 a0 = NA[2 * j], a1 = NA[2 * j + 1];
      short8 w;
      w[0] = (short)f2bf(a0[0]); w[1] = (short)f2bf(a0[1]);
      w[2] = (short)f2bf(a0[2]); w[3] = (short)f2bf(a0[3]);
      w[4] = (short)f2bf(a1[0]); w[5] = (short)f2bf(a1[1]);
      w[6] = (short)f2bf(a1[2]); w[7] = (short)f2bf(a1[3]);
      W[j] = w;
    }
  }

  // Epilogue: cross-wave reduction, red[] aliased into As (32 KB of 128 KB).
  __syncthreads();  // all frag ds_reads done before overwrite
  float* const red = (float*)As;
  #pragma unroll
  for (int r = 0; r < 4; ++r) {
    red[wave * 512 + (q * 4 + r) * 32 + c]      = acc0[r];
    red[wave * 512 + (q * 4 + r) * 32 + 16 + c] = acc1[r];
  }
  __syncthreads();

  // thread -> (m_local = tid>>5, n = tid&31); sum the 8 kgroup-waves of its msub.
  const int m_local = tid >> 5;
  const int n   = tid & 31;
  const int ms  = m_local >> 4;
  const int r16 = m_local & 15;
  float v = 0.f;
  #pragma unroll
  for (int g = 0; g < 8; ++g)
    v += red[(ms * 8 + g) * 512 + r16 * 32 + n];
  out[(size_t)(m0 + m_local) * DD + n] = fmaxf(v, 0.f);
}

extern "C" void kernel_launch(void* const* d_in, const int* in_sizes, int n_in,
                              void* d_out, int out_size, void* d_ws, size_t ws_size,
                              hipStream_t stream) {
  const float* x   = (const float*)d_in[0];  // [8192, 32]
  const float* adj = (const float*)d_in[1];  // [3, 8192, 8192]
  const float* W   = (const float*)d_in[2];  // [3, 32, 32]
  const float* b   = (const float*)d_in[3];  // [3, 32]
  float* out = (float*)d_out;                // [8192, 32]
  unsigned short* preT = (unsigned short*)d_ws;  // [3][32][8192] bf16 = 1.5 MB

  dim3 g1(NN / 256, SS);
  pre_kernel<<<g1, 256, 0, stream>>>(x, W, b, preT);
  prop_kernel<<<NN / MT, 1024, 0, stream>>>(adj, preT, out);
}